// Round 8
// baseline (209.768 us; speedup 1.0000x reference)
//
#include <hip/hip_runtime.h>

#define N_TOK  8192
#define KDIM   4096
#define NE     16
#define NSLICE 8                   // ws partials per token
#define TB     64                  // tokens per block (= wave width)
#define GPAD   513                 // gate chunk stride in float4 (512 + 1 pad)

// R14: per-row k-window rotation to break power-of-2 address aliasing.
// R13 (gate in LDS) improved partial 107->80.7us but VALUBusy=11%, BW=2.37
// TB/s, FETCH=183MB (ideal 138). Residual theory: every wave reads the SAME
// 512B k-window of 64 rows spaced exactly 16KB apart -> without address
// hashing, all requests of a wave (for its whole life) hit one HBM
// channel-slot and one L2 set group. Per strip-class: 4.2MB through ~1
// channel ~= 68us serial channel time ~= measured 80. Also explains +33%
// FETCH (L2 set-conflict evictions) and why all TLP/burst probes were flat.
// Fix: slice q = windows {q, q+8, q+16, q+24} (4KB apart). Wave w, row r
// reads window q+8*((w+lane)&3): one instruction's 64 requests spread over
// 4 channel-slots / 4 L2 set groups; across the 4 waves each row still gets
// all 4 windows exactly once -> ws[q] = valid permutation-sum, finalize
// unchanged. Gate: 4x8KB chunks staged to LDS, padded to 513 float4/chunk
// so the 4 per-lane-group reads hit disjoint bank quads (2052%32=4 ->
// groups 0/4/8/12, conflict-free broadcast).
// Prediction: partial 80.7 -> 35-45us, BW -> 4.5-5.5 TB/s, FETCH -> ~145MB,
// total -> ~155-170. Partial>=50: widen rotation to 8. Flat: theory dead.
__global__ __launch_bounds__(256, 4)
void router_partial(const float* __restrict__ x, const float* __restrict__ gate,
                    float* __restrict__ ws) {
  __shared__ __align__(16) float glds[4 * GPAD * 4];   // 32.8KB; reused as red[]
  const int tid  = threadIdx.x;
  const int lane = tid & 63;
  const int w    = __builtin_amdgcn_readfirstlane(tid >> 6);
  const int g    = blockIdx.x >> 3;          // token group (128)
  const int q    = blockIdx.x & 7;           // slice id -> ws slice
  const int t0   = g * TB;

  // ---- stage gate windows {q, q+8, q+16, q+24} (128 rows x 64B each) ----
  // 2048 float4; thread tid loads i=u*256+tid; chunk j=i>>9 (waves never
  // straddle chunks since 256|512), dst padded by 1 float4 per chunk.
  {
    const float4* gsrc = (const float4*)gate;          // float4 idx = k*4+s
    float4* gdst = (float4*)glds;
#pragma unroll
    for (int u = 0; u < 8; ++u) {
      int i = u * 256 + tid;
      int j = i >> 9, o = i & 511;
      gdst[j * GPAD + o] = gsrc[(size_t)(q + 8 * j) * 512 + o];
    }
  }
  __syncthreads();
  const float4* gl4 = (const float4*)glds;

  // per-lane rotated window: j in 0..3, window index q+8j, k0 = (q+8j)*128
  const int j   = (w + lane) & 3;
  const int gj  = j * GPAD;                  // gate LDS base (float4)
  const float4* xr = (const float4*)(x + (size_t)(t0 + lane) * KDIM
                                       + (size_t)(q + 8 * j) * 128);

  float acc[NE];
#pragma unroll
  for (int e = 0; e < NE; ++e) acc[e] = 0.f;

  // x: 32 float4 per lane (512B window), 2-deep ping-pong (R13 structure).
  float4 cur[4], nxt[4];
#pragma unroll
  for (int u = 0; u < 4; ++u) cur[u] = xr[u];
#pragma unroll
  for (int jc = 0; jc < 8; ++jc) {
    if (jc < 7) {
#pragma unroll
      for (int u = 0; u < 4; ++u) nxt[u] = xr[(jc + 1) * 4 + u];
    }
#pragma unroll
    for (int u = 0; u < 4; ++u) {
      const float xv[4] = {cur[u].x, cur[u].y, cur[u].z, cur[u].w};
#pragma unroll
      for (int m = 0; m < 4; ++m) {
        const int kk = jc * 16 + u * 4 + m;  // k within window (compile-time)
        const float4 g0 = gl4[gj + kk * 4 + 0];  // 4 distinct addrs/wave,
        const float4 g1 = gl4[gj + kk * 4 + 1];  // disjoint bank quads ->
        const float4 g2 = gl4[gj + kk * 4 + 2];  // conflict-free broadcast
        const float4 g3 = gl4[gj + kk * 4 + 3];
        const float xm = xv[m];
        acc[0]  = fmaf(xm, g0.x, acc[0]);
        acc[1]  = fmaf(xm, g0.y, acc[1]);
        acc[2]  = fmaf(xm, g0.z, acc[2]);
        acc[3]  = fmaf(xm, g0.w, acc[3]);
        acc[4]  = fmaf(xm, g1.x, acc[4]);
        acc[5]  = fmaf(xm, g1.y, acc[5]);
        acc[6]  = fmaf(xm, g1.z, acc[6]);
        acc[7]  = fmaf(xm, g1.w, acc[7]);
        acc[8]  = fmaf(xm, g2.x, acc[8]);
        acc[9]  = fmaf(xm, g2.y, acc[9]);
        acc[10] = fmaf(xm, g2.z, acc[10]);
        acc[11] = fmaf(xm, g2.w, acc[11]);
        acc[12] = fmaf(xm, g3.x, acc[12]);
        acc[13] = fmaf(xm, g3.y, acc[13]);
        acc[14] = fmaf(xm, g3.z, acc[14]);
        acc[15] = fmaf(xm, g3.w, acc[15]);
      }
    }
#pragma unroll
    for (int u = 0; u < 4; ++u) cur[u] = nxt[u];
  }

  // cross-wave reduction: waves hold different windows of the same rows;
  // sum -> slice-q partial (permutation-complete). Reuse glds as red[256][17].
  __syncthreads();
  float* red = glds;
#pragma unroll
  for (int e = 0; e < NE; ++e) red[(w * 64 + lane) * 17 + e] = acc[e];
  __syncthreads();
  {
    int p0 = tid * 4;                        // 1024 (token,e) pairs, 4/thread
    int t  = p0 >> 4, e0 = p0 & 15;
    float v[4];
#pragma unroll
    for (int jj = 0; jj < 4; ++jj) {
      float sum = 0.f;
#pragma unroll
      for (int ww = 0; ww < 4; ++ww) sum += red[(ww * 64 + t) * 17 + e0 + jj];
      v[jj] = sum;
    }
    *(float4*)(ws + ((size_t)q * N_TOK + (t0 + t)) * NE + e0) =
        make_float4(v[0], v[1], v[2], v[3]);
  }
}

// Sum 8 slice partials, top-2 (earliest-index tie-break = jax top_k),
// sigmoid, scatter into (E,N) scores; token_indices[e][t] = t (as float).
__global__ __launch_bounds__(256)
void router_finalize(const float* __restrict__ ws, float* __restrict__ out) {
  int t = blockIdx.x * 256 + threadIdx.x;
  float l[NE];
#pragma unroll
  for (int e = 0; e < NE; ++e) l[e] = 0.f;
#pragma unroll
  for (int s = 0; s < NSLICE; ++s) {
    const float4* row = (const float4*)(ws + ((size_t)s * N_TOK + t) * NE);
    float4 r0 = row[0], r1 = row[1], r2 = row[2], r3 = row[3];
    l[0]  += r0.x; l[1]  += r0.y; l[2]  += r0.z; l[3]  += r0.w;
    l[4]  += r1.x; l[5]  += r1.y; l[6]  += r1.z; l[7]  += r1.w;
    l[8]  += r2.x; l[9]  += r2.y; l[10] += r2.z; l[11] += r2.w;
    l[12] += r3.x; l[13] += r3.y; l[14] += r3.z; l[15] += r3.w;
  }
  int i1 = 0; float v1 = l[0];
#pragma unroll
  for (int e = 1; e < NE; ++e) { if (l[e] > v1) { v1 = l[e]; i1 = e; } }
  int i2 = -1; float v2 = -1e30f;
#pragma unroll
  for (int e = 0; e < NE; ++e) { if (e != i1 && l[e] > v2) { v2 = l[e]; i2 = e; } }
  float s1 = 1.f / (1.f + __expf(-v1));
  float s2 = 1.f / (1.f + __expf(-v2));
  float* scores = out;
  float* tix    = out + (size_t)NE * N_TOK;
  float tf = (float)t;
#pragma unroll
  for (int e = 0; e < NE; ++e) {             // coalesced across lanes per e
    scores[(size_t)e * N_TOK + t] = (e == i1) ? s1 : ((e == i2) ? s2 : 0.f);
    tix[(size_t)e * N_TOK + t]    = tf;
  }
}

extern "C" void kernel_launch(void* const* d_in, const int* in_sizes, int n_in,
                              void* d_out, int out_size, void* d_ws, size_t ws_size,
                              hipStream_t stream) {
  const float* x    = (const float*)d_in[0];
  const float* gate = (const float*)d_in[1];
  float* out = (float*)d_out;
  float* ws  = (float*)d_ws;   // needs NSLICE*N_TOK*NE*4 = 4 MB
  router_partial<<<dim3(N_TOK / TB * NSLICE), dim3(256), 0, stream>>>(x, gate, ws);
  router_finalize<<<dim3(N_TOK / 256), dim3(256), 0, stream>>>(ws, out);
}

// Round 9
// 192.757 us; speedup vs baseline: 1.0883x; 1.0883x over previous
//
#include <hip/hip_runtime.h>

#define N_TOK 8192
#define KDIM  4096
#define NE    16
#define TPB   8                    // tokens per block
#define CHUNK 256                  // k per chunk
#define NC    (KDIM / CHUNK)       // 16 chunks
#define GSTR  260                  // gateT row stride in floats (256 + 4 pad)
#define GBUF  (NE * GSTR)          // 4160 floats per LDS buffer

// R15: coalesced row-streaming GEMV (structural rewrite).
// Evidence: fill=6.9TB/s (1KB contiguous/instr); our lane=token pattern
// (64 scattered 64B lines at 16KB stride per instr) = 2.3TB/s under FIVE
// different configs (TLP 8/16/32w, run 256B/512B/1KB, burst, rotation) ->
// the scatter IS the cap. R6 had coalesced reads but died of vmcnt(0)+
// barrier drains on 32KB HBM x-tiles. R15: wave owns 2 token ROWS, lanes
// split k -> per chunk, lane l reads x[tok][c*256+4l..+3] = one contiguous
// 1KB instruction, rows streamed start-to-end (fill-shaped). Gate chunk
// (16KB, L2-hot) transposed to LDS double-buffer via reg staging
// (issue-early/write-late, T14); ONE barrier per chunk, drain is tiny LDS
// writes, not HBM. acc[t][e] per lane over its k-partition; epilogue: 3x
// shfl_xor (32/16/8) -> 8 groups, 4KB LDS gather, coalesced logits write.
// ws = full logits (512KB); finalize = top2 only. VGPR ~95 -> 4 blk/CU =
// 16 waves/CU (measured sweet spot).
// Prediction: logits ~25-32us, BW 4.5-5.5TB/s, VALUBusy 25-35%, FETCH
// ~140MB, total ~150-165. 50-70us+low VALU => barrier serialization back.
__global__ __launch_bounds__(256, 4)
void router_logits(const float* __restrict__ x, const float* __restrict__ gate,
                   float* __restrict__ ws) {
  __shared__ __align__(16) float glds[2 * GBUF];   // 33.3 KB
  const int tid  = threadIdx.x;
  const int lane = tid & 63;
  const int w    = __builtin_amdgcn_readfirstlane(tid >> 6);
  const int t0   = blockIdx.x * TPB;
  const int tokb = t0 + w * 2;                     // wave's 2 tokens

  const float4* gsrc = (const float4*)gate;        // f4 idx: k*4 + j

  // ---- prologue: stage gate chunk 0 into buf0, issue chunk 1 ----
  float4 gr[4];
#pragma unroll
  for (int u = 0; u < 4; ++u) gr[u] = gsrc[u * 256 + tid];
#pragma unroll
  for (int u = 0; u < 4; ++u) {                    // transpose write: gateT[e][k]
    int f4 = u * 256 + tid, k = f4 >> 2, j = f4 & 3;
    glds[(4 * j + 0) * GSTR + k] = gr[u].x;
    glds[(4 * j + 1) * GSTR + k] = gr[u].y;
    glds[(4 * j + 2) * GSTR + k] = gr[u].z;
    glds[(4 * j + 3) * GSTR + k] = gr[u].w;
  }
#pragma unroll
  for (int u = 0; u < 4; ++u) gr[u] = gsrc[1024 + u * 256 + tid];

  const float4* xr0 = (const float4*)(x + (size_t)(tokb + 0) * KDIM);
  const float4* xr1 = (const float4*)(x + (size_t)(tokb + 1) * KDIM);
  float4 xc0 = xr0[lane], xc1 = xr1[lane];         // chunk 0: 1KB/instr/wave

  float acc[2][NE];
#pragma unroll
  for (int t = 0; t < 2; ++t)
#pragma unroll
    for (int e = 0; e < NE; ++e) acc[t][e] = 0.f;

  __syncthreads();                                 // buf0 visible

  const float4* gl4 = (const float4*)glds;
  for (int c = 0; c < NC; ++c) {
    const int b = c & 1;
    // issue next x chunk (independent, hoisted to top)
    float4 xn0 = xc0, xn1 = xc1;
    if (c + 1 < NC) { xn0 = xr0[(c + 1) * 64 + lane]; xn1 = xr1[(c + 1) * 64 + lane]; }

    // compute chunk c from buf b: per e-quarter, 4 ds_read_b128 + 32 FMA
    const float4* gb4 = gl4 + b * (GBUF / 4);
#pragma unroll
    for (int eq = 0; eq < 4; ++eq) {
      const float4 ge0 = gb4[(eq * 4 + 0) * 65 + lane];
      const float4 ge1 = gb4[(eq * 4 + 1) * 65 + lane];
      const float4 ge2 = gb4[(eq * 4 + 2) * 65 + lane];
      const float4 ge3 = gb4[(eq * 4 + 3) * 65 + lane];
      acc[0][eq*4+0] += xc0.x*ge0.x + xc0.y*ge0.y + xc0.z*ge0.z + xc0.w*ge0.w;
      acc[0][eq*4+1] += xc0.x*ge1.x + xc0.y*ge1.y + xc0.z*ge1.z + xc0.w*ge1.w;
      acc[0][eq*4+2] += xc0.x*ge2.x + xc0.y*ge2.y + xc0.z*ge2.z + xc0.w*ge2.w;
      acc[0][eq*4+3] += xc0.x*ge3.x + xc0.y*ge3.y + xc0.z*ge3.z + xc0.w*ge3.w;
      acc[1][eq*4+0] += xc1.x*ge0.x + xc1.y*ge0.y + xc1.z*ge0.z + xc1.w*ge0.w;
      acc[1][eq*4+1] += xc1.x*ge1.x + xc1.y*ge1.y + xc1.z*ge1.z + xc1.w*ge1.w;
      acc[1][eq*4+2] += xc1.x*ge2.x + xc1.y*ge2.y + xc1.z*ge2.z + xc1.w*ge2.w;
      acc[1][eq*4+3] += xc1.x*ge3.x + xc1.y*ge3.y + xc1.z*ge3.z + xc1.w*ge3.w;
    }

    // stage gate chunk c+1 into buf b^1 (readers of b^1 finished at the
    // barrier ending iteration c-1); then issue chunk c+2 loads
    if (c + 1 < NC) {
#pragma unroll
      for (int u = 0; u < 4; ++u) {
        int f4 = u * 256 + tid, k = f4 >> 2, j = f4 & 3;
        float* dst = glds + (b ^ 1) * GBUF;
        dst[(4 * j + 0) * GSTR + k] = gr[u].x;
        dst[(4 * j + 1) * GSTR + k] = gr[u].y;
        dst[(4 * j + 2) * GSTR + k] = gr[u].z;
        dst[(4 * j + 3) * GSTR + k] = gr[u].w;
      }
      if (c + 2 < NC) {
#pragma unroll
        for (int u = 0; u < 4; ++u) gr[u] = gsrc[(c + 2) * 1024 + u * 256 + tid];
      }
    }
    xc0 = xn0; xc1 = xn1;
    __syncthreads();   // buf b readers done (next iter writes b) + b^1 writes visible
  }

  // ---- epilogue: lane-k-partition reduce ----
  // 3 xor steps -> 8 groups (by lane&7), each holding sum over 8 lanes' k-sets
#pragma unroll
  for (int t = 0; t < 2; ++t)
#pragma unroll
    for (int e = 0; e < NE; ++e) {
      acc[t][e] += __shfl_xor(acc[t][e], 32, 64);
      acc[t][e] += __shfl_xor(acc[t][e], 16, 64);
      acc[t][e] += __shfl_xor(acc[t][e],  8, 64);
    }
  // red[w][g][t][e] in glds (4KB region of buf0; all LDS reads are done)
  if (lane < 8) {
#pragma unroll
    for (int t = 0; t < 2; ++t)
#pragma unroll
      for (int e = 0; e < NE; ++e)
        glds[((w * 8 + lane) * 2 + t) * 16 + e] = acc[t][e];
  }
  __syncthreads();
  if (tid < 128) {                                 // one (token, e) per thread
    int tb = tid >> 4, e = tid & 15, ww = tb >> 1, tt = tb & 1;
    float s = 0.f;
#pragma unroll
    for (int g = 0; g < 8; ++g) s += glds[((ww * 8 + g) * 2 + tt) * 16 + e];
    ws[(size_t)t0 * NE + tid] = s;                 // = ws[(t0+tb)*16+e], coalesced
  }
}

// Read full logits, top-2 (earliest-index tie-break = jax top_k), sigmoid,
// scatter into (E,N) scores; token_indices[e][t] = t (as float).
__global__ __launch_bounds__(256)
void router_finalize(const float* __restrict__ ws, float* __restrict__ out) {
  int t = blockIdx.x * 256 + threadIdx.x;
  const float4* row = (const float4*)(ws + (size_t)t * NE);
  float4 r0 = row[0], r1 = row[1], r2 = row[2], r3 = row[3];
  float l[NE] = {r0.x, r0.y, r0.z, r0.w, r1.x, r1.y, r1.z, r1.w,
                 r2.x, r2.y, r2.z, r2.w, r3.x, r3.y, r3.z, r3.w};
  int i1 = 0; float v1 = l[0];
#pragma unroll
  for (int e = 1; e < NE; ++e) { if (l[e] > v1) { v1 = l[e]; i1 = e; } }
  int i2 = -1; float v2 = -1e30f;
#pragma unroll
  for (int e = 0; e < NE; ++e) { if (e != i1 && l[e] > v2) { v2 = l[e]; i2 = e; } }
  float s1 = 1.f / (1.f + __expf(-v1));
  float s2 = 1.f / (1.f + __expf(-v2));
  float* scores = out;
  float* tix    = out + (size_t)NE * N_TOK;
  float tf = (float)t;
#pragma unroll
  for (int e = 0; e < NE; ++e) {                   // coalesced across lanes per e
    scores[(size_t)e * N_TOK + t] = (e == i1) ? s1 : ((e == i2) ? s2 : 0.f);
    tix[(size_t)e * N_TOK + t]    = tf;
  }
}

extern "C" void kernel_launch(void* const* d_in, const int* in_sizes, int n_in,
                              void* d_out, int out_size, void* d_ws, size_t ws_size,
                              hipStream_t stream) {
  const float* x    = (const float*)d_in[0];
  const float* gate = (const float*)d_in[1];
  float* out = (float*)d_out;
  float* ws  = (float*)d_ws;   // needs N_TOK*NE*4 = 512 KB (full logits)
  router_logits<<<dim3(N_TOK / TPB), dim3(256), 0, stream>>>(x, gate, ws);
  router_finalize<<<dim3(N_TOK / 256), dim3(256), 0, stream>>>(ws, out);
}